// Round 10
// baseline (132.603 us; speedup 1.0000x reference)
//
#include <hip/hip_runtime.h>
#include <math.h>

// ROUND 10 = MEASUREMENT ROUND: all pure kernels launched TWICE (idempotent).
// dur_delta vs R9 (105.8us) = T(moments)+T(escan)*2+T(stage1)+T(stage2_rhs)+5*gap.
// Collide (non-idempotent) launched once. Output bit-identical to R9.

#define NX 2048
#define NV 1024

static constexpr float DXf    = 1.0f / 2048.0f;
static constexpr float DVf    = 12.0f / 1024.0f;
static constexpr float DTf    = 0.001f;
static constexpr float INV_DX = 2048.0f;
static constexpr float INV_DV = 1024.0f / 12.0f;

// minmod(a,b) == median(a, b, 0): single v_med3_f32 on gfx950.
__device__ __forceinline__ float minmod_f(float a, float b) {
    return __builtin_amdgcn_fmed3f(a, b, 0.0f);
}

// Raw v_rcp_f32 (rel err ~1e-5): Newton step sat on the Thomas serial chain.
__device__ __forceinline__ float frcp(float x) {
    return __builtin_amdgcn_rcpf(x);
}

// XCD-chunked swizzles: XCD k owns a contiguous row range.
__device__ __forceinline__ int swz2048(int x) {
    return ((x & 7) << 8) + (x >> 3);
}
__device__ __forceinline__ int swz512(int x) {
    return ((x & 7) << 6) + (x >> 3);
}

// Vectorized MUSCL rhs for 8 contiguous cells j0..j0+7 (j0 % 8 == 0).
__device__ __forceinline__ void rhs8(const float* __restrict__ g, int i, int j0, float Ecs,
                                     float* __restrict__ f0o, float* __restrict__ ro) {
    const float* rowc = g + (size_t)i * NV;
    const float* rm1  = g + (size_t)((i - 1) & (NX - 1)) * NV;
    const float* rm2  = g + (size_t)((i - 2) & (NX - 1)) * NV;
    const float* rp1  = g + (size_t)((i + 1) & (NX - 1)) * NV;
    const float* rp2  = g + (size_t)((i + 2) & (NX - 1)) * NV;

    float4 c0  = *(const float4*)(rowc + j0);
    float4 c1  = *(const float4*)(rowc + j0 + 4);
    float4 a10 = *(const float4*)(rm1 + j0);
    float4 a11 = *(const float4*)(rm1 + j0 + 4);
    float4 a20 = *(const float4*)(rm2 + j0);
    float4 a21 = *(const float4*)(rm2 + j0 + 4);
    float4 p10 = *(const float4*)(rp1 + j0);
    float4 p11 = *(const float4*)(rp1 + j0 + 4);
    float4 p20 = *(const float4*)(rp2 + j0);
    float4 p21 = *(const float4*)(rp2 + j0 + 4);
    float4 lm = make_float4(0.f, 0.f, 0.f, 0.f);
    float4 rp = make_float4(0.f, 0.f, 0.f, 0.f);
    if (j0 >= 4)           lm = *(const float4*)(rowc + j0 - 4);
    if (j0 + 8 <= NV - 4)  rp = *(const float4*)(rowc + j0 + 8);

    float vals[12] = {lm.z, lm.w,
                      c0.x, c0.y, c0.z, c0.w, c1.x, c1.y, c1.z, c1.w,
                      rp.x, rp.y};
    float cc[8]  = {c0.x, c0.y, c0.z, c0.w, c1.x, c1.y, c1.z, c1.w};
    float am1[8] = {a10.x, a10.y, a10.z, a10.w, a11.x, a11.y, a11.z, a11.w};
    float am2[8] = {a20.x, a20.y, a20.z, a20.w, a21.x, a21.y, a21.z, a21.w};
    float ap1[8] = {p10.x, p10.y, p10.z, p10.w, p11.x, p11.y, p11.z, p11.w};
    float ap2[8] = {p20.x, p20.y, p20.z, p20.w, p21.x, p21.y, p21.z, p21.w};

    #pragma unroll
    for (int k = 0; k < 8; ++k) {
        float f0  = cc[k];
        float fm1 = am1[k], fm2 = am2[k], fp1 = ap1[k], fp2 = ap2[k];

        float vx = (DVf * ((float)(j0 + k) + 0.5f) - 6.0f) * INV_DX;
        float dm1 = fm1 - fm2, d0 = f0 - fm1, dp1 = fp1 - f0, dp2 = fp2 - fp1;
        float sm1 = minmod_f(dm1, d0);
        float s0  = minmod_f(d0, dp1);
        float sp1 = minmod_f(dp1, dp2);
        float selx = (vx > 0.0f) ? (d0 + 0.5f * (s0 - sm1))
                                 : (dp1 - 0.5f * (sp1 - s0));
        float vdfdx = vx * selx;

        float gm2 = vals[k], gm1 = vals[k + 1], gp1 = vals[k + 3], gp2 = vals[k + 4];
        float em1 = gm1 - gm2, e0 = f0 - gm1, ep1 = gp1 - f0, ep2 = gp2 - gp1;
        float tm1 = minmod_f(em1, e0);
        float t0  = minmod_f(e0, ep1);
        float tp1 = minmod_f(ep1, ep2);
        float selv = (Ecs > 0.0f) ? (e0 + 0.5f * (t0 - tm1))
                                  : (ep1 - 0.5f * (tp1 - t0));
        float Edfdv = Ecs * selv;

        f0o[k] = f0;
        ro[k]  = -vdfdx - Edfdv;
    }
}

// K1: row sums of fe and fi. 512 blocks; wave wv owns row 4g+wv (both species).
__global__ __launch_bounds__(256) void moments_kernel(const float* __restrict__ fe,
                                                      const float* __restrict__ fi,
                                                      float* __restrict__ se,
                                                      float* __restrict__ si) {
    const int g = swz512(blockIdx.x);
    const int t = threadIdx.x, lane = t & 63, wv = t >> 6;
    const int row = (g << 2) + wv;
    const float* rpe = fe + (size_t)row * NV;
    const float* rpi = fi + (size_t)row * NV;
    float a = 0.0f, b = 0.0f;
    #pragma unroll
    for (int q = 0; q < 4; ++q) {
        float4 x = *(const float4*)(rpe + 4 * lane + 256 * q);
        float4 y = *(const float4*)(rpi + 4 * lane + 256 * q);
        a += x.x + x.y + x.z + x.w;
        b += y.x + y.y + y.z + y.w;
    }
    #pragma unroll
    for (int off = 32; off > 0; off >>= 1) {
        a += __shfl_down(a, off, 64);
        b += __shfl_down(b, off, 64);
    }
    if (lane == 0) { se[row] = a; si[row] = b; }
}

// K2/K4: single-block field solve. E[i] = DX*(P_i - W/NX).
__global__ __launch_bounds__(256) void escan_kernel(const float* __restrict__ se_,
                                                    const float* __restrict__ si_,
                                                    float* __restrict__ E) {
    const int t = threadIdx.x, lane = t & 63, wv = t >> 6;
    const int k0 = t * 8;
    float4 a0 = *(const float4*)(se_ + k0);
    float4 a1 = *(const float4*)(se_ + k0 + 4);
    float4 b0 = *(const float4*)(si_ + k0);
    float4 b1 = *(const float4*)(si_ + k0 + 4);
    float rho[8];
    rho[0] = DVf * (b0.x - a0.x); rho[1] = DVf * (b0.y - a0.y);
    rho[2] = DVf * (b0.z - a0.z); rho[3] = DVf * (b0.w - a0.w);
    rho[4] = DVf * (b1.x - a1.x); rho[5] = DVf * (b1.y - a1.y);
    rho[6] = DVf * (b1.z - a1.z); rho[7] = DVf * (b1.w - a1.w);
    float s = 0.0f, w = 0.0f;
    #pragma unroll
    for (int r = 0; r < 8; ++r) {
        s += rho[r];
        w += rho[r] * (float)(NX - (k0 + r));
    }
    float sc = s;
    #pragma unroll
    for (int off = 1; off < 64; off <<= 1) {
        float u = __shfl_up(sc, off, 64);
        if (lane >= off) sc += u;
    }
    #pragma unroll
    for (int off = 32; off > 0; off >>= 1) w += __shfl_down(w, off, 64);
    __shared__ float wsum[4], wtot[4];
    if (lane == 63) wsum[wv] = sc;
    if (lane == 0)  wtot[wv] = w;
    __syncthreads();
    float base = 0.0f;
    #pragma unroll
    for (int u = 0; u < 4; ++u) if (u < wv) base += wsum[u];
    float W = wtot[0] + wtot[1] + wtot[2] + wtot[3];
    float run = base + sc - s;
    const float mean = W * (1.0f / (float)NX);
    #pragma unroll
    for (int r = 0; r < 8; ++r) {
        run += rho[r];
        E[k0 + r] = DXf * (run - mean);
    }
}

// K3: f1 = f + dt*rhs(f); row sums of f1. grid (2048, 2); 128 thr, 8 cells/thread.
__global__ __launch_bounds__(128) void stage1_kernel(const float* __restrict__ fe,
                                                     const float* __restrict__ fi,
                                                     const float* __restrict__ E0,
                                                     float* __restrict__ fe1,
                                                     float* __restrict__ fi1,
                                                     float* __restrict__ se1,
                                                     float* __restrict__ si1) {
    const int row = swz2048(blockIdx.x);
    const int sp  = blockIdx.y;
    const float* f = sp ? fi : fe;
    float* f1 = sp ? fi1 : fe1;
    const float zoa = sp ? (1.0f / 1836.0f) : -1.0f;
    const float Ecs = zoa * E0[row] * INV_DV;
    const int t = threadIdx.x, lane = t & 63, wv = t >> 6;
    const int j0 = 8 * t;

    float f0[8], rv[8], o[8];
    rhs8(f, row, j0, Ecs, f0, rv);
    float s = 0.0f;
    #pragma unroll
    for (int k = 0; k < 8; ++k) {
        o[k] = f0[k] + DTf * rv[k];
        s += o[k];
    }
    float* orow = f1 + (size_t)row * NV + j0;
    *(float4*)(orow)     = make_float4(o[0], o[1], o[2], o[3]);
    *(float4*)(orow + 4) = make_float4(o[4], o[5], o[6], o[7]);

    #pragma unroll
    for (int off = 32; off > 0; off >>= 1) s += __shfl_down(s, off, 64);
    __shared__ float sred[2];
    if (lane == 0) sred[wv] = s;
    __syncthreads();
    if (t == 0) (sp ? si1 : se1)[row] = sred[0] + sred[1];
}

// K5: stage-2 rhs only — g2 = 0.5*h + 0.5*f1 + 0.5*dt*rhs(f1), written into OUT.
__global__ __launch_bounds__(128) void stage2_rhs_kernel(const float* __restrict__ fe,
                                                         const float* __restrict__ fi,
                                                         const float* __restrict__ fe1,
                                                         const float* __restrict__ fi1,
                                                         const float* __restrict__ E1,
                                                         float* __restrict__ out) {
    const int row = swz2048(blockIdx.x);
    const int sp  = blockIdx.y;
    const float* h  = sp ? fi : fe;
    const float* f1 = sp ? fi1 : fe1;
    const float zoa = sp ? (1.0f / 1836.0f) : -1.0f;
    const float Ecs = zoa * E1[row] * INV_DV;
    const int t = threadIdx.x;
    const int j0 = 8 * t;
    float* orow = out + ((size_t)sp * NX + row) * NV + j0;

    float f0[8], rv[8];
    rhs8(f1, row, j0, Ecs, f0, rv);
    float4 h0 = *(const float4*)(h + (size_t)row * NV + j0);
    float4 h1 = *(const float4*)(h + (size_t)row * NV + j0 + 4);
    float hh[8] = {h0.x, h0.y, h0.z, h0.w, h1.x, h1.y, h1.z, h1.w};
    float o[8];
    #pragma unroll
    for (int k = 0; k < 8; ++k)
        o[k] = 0.5f * hh[k] + 0.5f * f0[k] + (0.5f * DTf) * rv[k];
    *(float4*)(orow)     = make_float4(o[0], o[1], o[2], o[3]);
    *(float4*)(orow + 4) = make_float4(o[4], o[5], o[6], o[7]);
}

// K6: implicit LBO collide, in place on OUT. grid (512, 2); 256 threads, wave wv
// owns row 4g+wv. NOT idempotent -> launched once.
__global__ __launch_bounds__(256) void collide_kernel(float* __restrict__ out) {
    const int g  = swz512(blockIdx.x);
    const int sp = blockIdx.y;
    const int t = threadIdx.x, lane = t & 63, wv = t >> 6;
    const int row = (g << 2) + wv;
    const float lam = sp ? 0.1f : 1.0f;
    float* orow = out + ((size_t)sp * NX + row) * NV;

    const float Tdv2   = 1.0f / (DVf * DVf);
    const float inv2dv = 0.5f / DVf;
    const float xi = DXf * ((float)row + 0.5f) - 0.5f;
    const float nu = 1.0f / (1.0f + 0.5f * (expf(60.0f * xi - 20.0f) + expf(-60.0f * xi - 20.0f)));
    const float K = DTf * nu * lam;
    const float b = 1.0f + 2.0f * K * Tdv2;

    const int j0 = 16 * lane;

    float4 q0 = *(const float4*)(orow + j0);
    float4 q1 = *(const float4*)(orow + j0 + 4);
    float4 q2 = *(const float4*)(orow + j0 + 8);
    float4 q3 = *(const float4*)(orow + j0 + 12);
    float d[16] = {q0.x, q0.y, q0.z, q0.w, q1.x, q1.y, q1.z, q1.w,
                   q2.x, q2.y, q2.z, q2.w, q3.x, q3.y, q3.z, q3.w};

    float Dv[16], Av[16], Cv[16];
    #pragma unroll
    for (int r = 0; r < 16; ++r) {
        const int j = j0 + r;
        float a = (j == 0)      ? 0.0f : -K * (Tdv2 - (DVf * ((float)j - 0.5f) - 6.0f) * inv2dv);
        float c = (j == NV - 1) ? 0.0f : -K * (Tdv2 + (DVf * ((float)j + 1.5f) - 6.0f) * inv2dv);
        if (r == 0) {
            float e = frcp(b);
            Dv[0] = e * d[0];
            Av[0] = e * a;
            Cv[0] = e * c;
        } else {
            float e = frcp(b - a * Cv[r - 1]);
            Dv[r] = e * (d[r] - a * Dv[r - 1]);
            Av[r] = -e * a * Av[r - 1];
            Cv[r] = e * c;
        }
    }
    #pragma unroll
    for (int r = 14; r >= 0; --r) {
        Dv[r] = Dv[r] - Cv[r] * Dv[r + 1];
        Av[r] = Av[r] - Cv[r] * Av[r + 1];
        Cv[r] = -Cv[r] * Cv[r + 1];
    }

    float la = Av[0],  ra = Cv[0],  d0 = Dv[0];
    float lb = Av[15], rb = Cv[15], d1 = Dv[15];
    #pragma unroll
    for (int s = 1; s < 64; s <<= 1) {
        float lb_m = __shfl_up(lb, s, 64);
        float rb_m = __shfl_up(rb, s, 64);
        float d1_m = __shfl_up(d1, s, 64);
        if (lane < s) { lb_m = 0.0f; rb_m = 0.0f; d1_m = 0.0f; }
        float la_p = __shfl_down(la, s, 64);
        float ra_p = __shfl_down(ra, s, 64);
        float d0_p = __shfl_down(d0, s, 64);
        if (lane + s > 63) { la_p = 0.0f; ra_p = 0.0f; d0_p = 0.0f; }

        float m00 = 1.0f - la * rb_m;
        float m01 = -ra * la_p;
        float m10 = -lb * rb_m;
        float m11 = 1.0f - rb * la_p;
        float idet = frcp(m00 * m11 - m01 * m10);

        float Lr0 = -la * lb_m, Lr1 = -lb * lb_m;
        float Rr0 = -ra * ra_p, Rr1 = -rb * ra_p;
        float e0 = d0 - la * d1_m - ra * d0_p;
        float e1 = d1 - lb * d1_m - rb * d0_p;

        la = idet * (m11 * Lr0 - m01 * Lr1);
        lb = idet * (m00 * Lr1 - m10 * Lr0);
        ra = idet * (m11 * Rr0 - m01 * Rr1);
        rb = idet * (m00 * Rr1 - m10 * Rr0);
        d0 = idet * (m11 * e0 - m01 * e1);
        d1 = idet * (m00 * e1 - m10 * e0);
    }
    float zl = __shfl_up(d1, 1, 64);
    if (lane == 0) zl = 0.0f;
    float yr = __shfl_down(d0, 1, 64);
    if (lane == 63) yr = 0.0f;

    #pragma unroll
    for (int r = 0; r < 16; ++r) Dv[r] = Dv[r] - Av[r] * zl - Cv[r] * yr;
    #pragma unroll
    for (int q = 0; q < 4; ++q) {
        float4 o;
        o.x = Dv[4 * q + 0];
        o.y = Dv[4 * q + 1];
        o.z = Dv[4 * q + 2];
        o.w = Dv[4 * q + 3];
        *(float4*)(orow + j0 + 4 * q) = o;
    }
}

extern "C" void kernel_launch(void* const* d_in, const int* in_sizes, int n_in,
                              void* d_out, int out_size, void* d_ws, size_t ws_size,
                              hipStream_t stream) {
    const float* fe = (const float*)d_in[0];
    const float* fi = (const float*)d_in[1];
    float* out = (float*)d_out;
    const size_t P = (size_t)NX * NV;

    float* fe1 = (float*)d_ws;
    float* fi1 = fe1 + P;
    float* se  = fi1 + P;
    float* si  = se + NX;
    float* se1 = si + NX;
    float* si1 = se1 + NX;
    float* E0  = si1 + NX;
    float* E1  = E0 + NX;

    dim3 rgrid(2048, 2);
    dim3 qgrid(512, 2);

    // MEASUREMENT: every pure kernel twice (idempotent); collide once.
    moments_kernel<<<512, 256, 0, stream>>>(fe, fi, se, si);
    moments_kernel<<<512, 256, 0, stream>>>(fe, fi, se, si);
    escan_kernel<<<1, 256, 0, stream>>>(se, si, E0);
    escan_kernel<<<1, 256, 0, stream>>>(se, si, E0);
    stage1_kernel<<<rgrid, 128, 0, stream>>>(fe, fi, E0, fe1, fi1, se1, si1);
    stage1_kernel<<<rgrid, 128, 0, stream>>>(fe, fi, E0, fe1, fi1, se1, si1);
    escan_kernel<<<1, 256, 0, stream>>>(se1, si1, E1);
    escan_kernel<<<1, 256, 0, stream>>>(se1, si1, E1);
    stage2_rhs_kernel<<<rgrid, 128, 0, stream>>>(fe, fi, fe1, fi1, E1, out);
    stage2_rhs_kernel<<<rgrid, 128, 0, stream>>>(fe, fi, fe1, fi1, E1, out);
    collide_kernel<<<qgrid, 256, 0, stream>>>(out);
}

// Round 11
// 104.746 us; speedup vs baseline: 1.2660x; 1.2660x over previous
//
#include <hip/hip_runtime.h>
#include <math.h>

#define NX 2048
#define NV 1024

static constexpr float DXf    = 1.0f / 2048.0f;
static constexpr float DVf    = 12.0f / 1024.0f;
static constexpr float DTf    = 0.001f;
static constexpr float INV_DX = 2048.0f;
static constexpr float INV_DV = 1024.0f / 12.0f;

// minmod(a,b) == median(a, b, 0): single v_med3_f32 on gfx950.
__device__ __forceinline__ float minmod_f(float a, float b) {
    return __builtin_amdgcn_fmed3f(a, b, 0.0f);
}

// Raw v_rcp_f32 (rel err ~1e-5).
__device__ __forceinline__ float frcp(float x) {
    return __builtin_amdgcn_rcpf(x);
}

// XCD-chunked swizzles: XCD k owns a contiguous row range.
__device__ __forceinline__ int swz2048(int x) {
    return ((x & 7) << 8) + (x >> 3);
}
__device__ __forceinline__ int swz512(int x) {
    return ((x & 7) << 6) + (x >> 3);
}

// In-block E for row i, from row-sum arrays (L2-hot, 16 KB reads per block).
// E[i] = DX*(P_i - W/NX), P_i = sum_{k<=i} rho_k, W = sum_k rho_k*(NX-k),
// rho_k = DV*(si[k]-se[k]). 256 threads; one barrier.
__device__ __forceinline__ float block_E(const float* __restrict__ se_,
                                         const float* __restrict__ si_,
                                         int i) {
    const int t = threadIdx.x, lane = t & 63, wv = t >> 6;
    const int k0 = t * 8;
    float4 a0 = *(const float4*)(se_ + k0);
    float4 a1 = *(const float4*)(se_ + k0 + 4);
    float4 b0 = *(const float4*)(si_ + k0);
    float4 b1 = *(const float4*)(si_ + k0 + 4);
    float rho[8];
    rho[0] = DVf * (b0.x - a0.x); rho[1] = DVf * (b0.y - a0.y);
    rho[2] = DVf * (b0.z - a0.z); rho[3] = DVf * (b0.w - a0.w);
    rho[4] = DVf * (b1.x - a1.x); rho[5] = DVf * (b1.y - a1.y);
    rho[6] = DVf * (b1.z - a1.z); rho[7] = DVf * (b1.w - a1.w);
    float pref = 0.0f, wtot = 0.0f;
    #pragma unroll
    for (int r = 0; r < 8; ++r) {
        const int k = k0 + r;
        if (k <= i) pref += rho[r];
        wtot += rho[r] * (float)(NX - k);
    }
    #pragma unroll
    for (int off = 32; off > 0; off >>= 1) {
        pref += __shfl_down(pref, off, 64);
        wtot += __shfl_down(wtot, off, 64);
    }
    __shared__ float sp_[4], sw_[4];
    if (lane == 0) { sp_[wv] = pref; sw_[wv] = wtot; }
    __syncthreads();
    float P = sp_[0] + sp_[1] + sp_[2] + sp_[3];
    float W = sw_[0] + sw_[1] + sw_[2] + sw_[3];
    return DXf * (P - W * (1.0f / (float)NX));
}

// Vectorized MUSCL rhs for 4 contiguous cells j0..j0+3 (j0 % 4 == 0).
// Ecs = (Z/A)*E[row]*INV_DV (pre-scaled). Factored flux divergence.
__device__ __forceinline__ void rhs4(const float* __restrict__ g, int i, int j0, float Ecs,
                                     float4& f0v, float4& rv) {
    const float* rowc = g + (size_t)i * NV;
    const float* rm1  = g + (size_t)((i - 1) & (NX - 1)) * NV;
    const float* rm2  = g + (size_t)((i - 2) & (NX - 1)) * NV;
    const float* rp1  = g + (size_t)((i + 1) & (NX - 1)) * NV;
    const float* rp2  = g + (size_t)((i + 2) & (NX - 1)) * NV;

    float4 c   = *(const float4*)(rowc + j0);
    float4 xm1 = *(const float4*)(rm1 + j0);
    float4 xm2 = *(const float4*)(rm2 + j0);
    float4 xp1 = *(const float4*)(rp1 + j0);
    float4 xp2 = *(const float4*)(rp2 + j0);
    float4 lm = make_float4(0.f, 0.f, 0.f, 0.f);
    float4 rp = make_float4(0.f, 0.f, 0.f, 0.f);
    if (j0 >= 4)      lm = *(const float4*)(rowc + j0 - 4);
    if (j0 <= NV - 8) rp = *(const float4*)(rowc + j0 + 4);

    float vals[8] = {lm.z, lm.w, c.x, c.y, c.z, c.w, rp.x, rp.y};
    const float* cc   = (const float*)&c;
    const float* am1  = (const float*)&xm1;
    const float* am2  = (const float*)&xm2;
    const float* ap1  = (const float*)&xp1;
    const float* ap2  = (const float*)&xp2;
    float* f0o = (float*)&f0v;
    float* ro  = (float*)&rv;

    #pragma unroll
    for (int k = 0; k < 4; ++k) {
        float f0  = cc[k];
        float fm1 = am1[k], fm2 = am2[k], fp1 = ap1[k], fp2 = ap2[k];

        float vx = (DVf * ((float)(j0 + k) + 0.5f) - 6.0f) * INV_DX;
        float dm1 = fm1 - fm2, d0 = f0 - fm1, dp1 = fp1 - f0, dp2 = fp2 - fp1;
        float sm1 = minmod_f(dm1, d0);
        float s0  = minmod_f(d0, dp1);
        float sp1 = minmod_f(dp1, dp2);
        float selx = (vx > 0.0f) ? (d0 + 0.5f * (s0 - sm1))
                                 : (dp1 - 0.5f * (sp1 - s0));
        float vdfdx = vx * selx;

        float gm2 = vals[k], gm1 = vals[k + 1], gp1 = vals[k + 3], gp2 = vals[k + 4];
        float em1 = gm1 - gm2, e0 = f0 - gm1, ep1 = gp1 - f0, ep2 = gp2 - gp1;
        float tm1 = minmod_f(em1, e0);
        float t0  = minmod_f(e0, ep1);
        float tp1 = minmod_f(ep1, ep2);
        float selv = (Ecs > 0.0f) ? (e0 + 0.5f * (t0 - tm1))
                                  : (ep1 - 0.5f * (tp1 - t0));
        float Edfdv = Ecs * selv;

        f0o[k] = f0;
        ro[k]  = -vdfdx - Edfdv;
    }
}

// K1: row sums of fe and fi. 512 blocks; wave wv owns row 4g+wv (both species).
__global__ __launch_bounds__(256) void moments_kernel(const float* __restrict__ fe,
                                                      const float* __restrict__ fi,
                                                      float* __restrict__ se,
                                                      float* __restrict__ si) {
    const int g = swz512(blockIdx.x);
    const int t = threadIdx.x, lane = t & 63, wv = t >> 6;
    const int row = (g << 2) + wv;
    const float* rpe = fe + (size_t)row * NV;
    const float* rpi = fi + (size_t)row * NV;
    float a = 0.0f, b = 0.0f;
    #pragma unroll
    for (int q = 0; q < 4; ++q) {
        float4 x = *(const float4*)(rpe + 4 * lane + 256 * q);
        float4 y = *(const float4*)(rpi + 4 * lane + 256 * q);
        a += x.x + x.y + x.z + x.w;
        b += y.x + y.y + y.z + y.w;
    }
    #pragma unroll
    for (int off = 32; off > 0; off >>= 1) {
        a += __shfl_down(a, off, 64);
        b += __shfl_down(b, off, 64);
    }
    if (lane == 0) { se[row] = a; si[row] = b; }
}

// K2: f1 = f + dt*rhs(f); E computed in-block from se/si; row sums of f1.
// grid (2048, 2); 256 thr, 4 cells/thread.
__global__ __launch_bounds__(256) void stage1_kernel(const float* __restrict__ fe,
                                                     const float* __restrict__ fi,
                                                     const float* __restrict__ se,
                                                     const float* __restrict__ si,
                                                     float* __restrict__ fe1,
                                                     float* __restrict__ fi1,
                                                     float* __restrict__ se1,
                                                     float* __restrict__ si1) {
    const int row = swz2048(blockIdx.x);
    const int sp  = blockIdx.y;
    const float* f = sp ? fi : fe;
    float* f1 = sp ? fi1 : fe1;
    const float zoa = sp ? (1.0f / 1836.0f) : -1.0f;
    const float Ecs = zoa * block_E(se, si, row) * INV_DV;
    const int t = threadIdx.x, lane = t & 63, wv = t >> 6;
    const int j0 = 4 * t;

    float4 f0v, rv;
    rhs4(f, row, j0, Ecs, f0v, rv);
    float4 o;
    o.x = f0v.x + DTf * rv.x;
    o.y = f0v.y + DTf * rv.y;
    o.z = f0v.z + DTf * rv.z;
    o.w = f0v.w + DTf * rv.w;
    *(float4*)(f1 + (size_t)row * NV + j0) = o;

    float s = o.x + o.y + o.z + o.w;
    #pragma unroll
    for (int off = 32; off > 0; off >>= 1) s += __shfl_down(s, off, 64);
    __shared__ float sred[4];
    if (lane == 0) sred[wv] = s;
    __syncthreads();
    if (t == 0) (sp ? si1 : se1)[row] = sred[0] + sred[1] + sred[2] + sred[3];
}

// K3: stage-2 rhs — g2 = 0.5*h + 0.5*f1 + 0.5*dt*rhs(f1) into OUT.
// E computed in-block from se1/si1. grid (2048, 2); 256 thr.
__global__ __launch_bounds__(256) void stage2_rhs_kernel(const float* __restrict__ fe,
                                                         const float* __restrict__ fi,
                                                         const float* __restrict__ fe1,
                                                         const float* __restrict__ fi1,
                                                         const float* __restrict__ se1,
                                                         const float* __restrict__ si1,
                                                         float* __restrict__ out) {
    const int row = swz2048(blockIdx.x);
    const int sp  = blockIdx.y;
    const float* h  = sp ? fi : fe;
    const float* f1 = sp ? fi1 : fe1;
    const float zoa = sp ? (1.0f / 1836.0f) : -1.0f;
    const float Ecs = zoa * block_E(se1, si1, row) * INV_DV;
    const int t = threadIdx.x;
    const int j0 = 4 * t;
    float* orow = out + ((size_t)sp * NX + row) * NV;

    float4 f0v, rv;
    rhs4(f1, row, j0, Ecs, f0v, rv);
    float4 h4 = *(const float4*)(h + (size_t)row * NV + j0);
    float4 o;
    o.x = 0.5f * h4.x + 0.5f * f0v.x + (0.5f * DTf) * rv.x;
    o.y = 0.5f * h4.y + 0.5f * f0v.y + (0.5f * DTf) * rv.y;
    o.z = 0.5f * h4.z + 0.5f * f0v.z + (0.5f * DTf) * rv.z;
    o.w = 0.5f * h4.w + 0.5f * f0v.w + (0.5f * DTf) * rv.w;
    *(float4*)(orow + j0) = o;
}

// K4: implicit LBO collide, in place on OUT. grid (512, 2); 256 threads, wave wv
// owns row 4g+wv. Waves fully independent: no LDS, no barriers.
__global__ __launch_bounds__(256) void collide_kernel(float* __restrict__ out) {
    const int g  = swz512(blockIdx.x);
    const int sp = blockIdx.y;
    const int t = threadIdx.x, lane = t & 63, wv = t >> 6;
    const int row = (g << 2) + wv;
    const float lam = sp ? 0.1f : 1.0f;
    float* orow = out + ((size_t)sp * NX + row) * NV;

    const float Tdv2   = 1.0f / (DVf * DVf);
    const float inv2dv = 0.5f / DVf;
    const float xi = DXf * ((float)row + 0.5f) - 0.5f;
    const float nu = 1.0f / (1.0f + 0.5f * (__expf(60.0f * xi - 20.0f) + __expf(-60.0f * xi - 20.0f)));
    const float K = DTf * nu * lam;
    const float b = 1.0f + 2.0f * K * Tdv2;

    const int j0 = 16 * lane;

    float4 q0 = *(const float4*)(orow + j0);
    float4 q1 = *(const float4*)(orow + j0 + 4);
    float4 q2 = *(const float4*)(orow + j0 + 8);
    float4 q3 = *(const float4*)(orow + j0 + 12);
    float d[16] = {q0.x, q0.y, q0.z, q0.w, q1.x, q1.y, q1.z, q1.w,
                   q2.x, q2.y, q2.z, q2.w, q3.x, q3.y, q3.z, q3.w};

    float Dv[16], Av[16], Cv[16];
    #pragma unroll
    for (int r = 0; r < 16; ++r) {
        const int j = j0 + r;
        float a = (j == 0)      ? 0.0f : -K * (Tdv2 - (DVf * ((float)j - 0.5f) - 6.0f) * inv2dv);
        float c = (j == NV - 1) ? 0.0f : -K * (Tdv2 + (DVf * ((float)j + 1.5f) - 6.0f) * inv2dv);
        if (r == 0) {
            float e = frcp(b);
            Dv[0] = e * d[0];
            Av[0] = e * a;
            Cv[0] = e * c;
        } else {
            float e = frcp(b - a * Cv[r - 1]);
            Dv[r] = e * (d[r] - a * Dv[r - 1]);
            Av[r] = -e * a * Av[r - 1];
            Cv[r] = e * c;
        }
    }
    #pragma unroll
    for (int r = 14; r >= 0; --r) {
        Dv[r] = Dv[r] - Cv[r] * Dv[r + 1];
        Av[r] = Av[r] - Cv[r] * Av[r + 1];
        Cv[r] = -Cv[r] * Cv[r + 1];
    }

    float la = Av[0],  ra = Cv[0],  d0 = Dv[0];
    float lb = Av[15], rb = Cv[15], d1 = Dv[15];
    #pragma unroll
    for (int s = 1; s < 64; s <<= 1) {
        float lb_m = __shfl_up(lb, s, 64);
        float rb_m = __shfl_up(rb, s, 64);
        float d1_m = __shfl_up(d1, s, 64);
        if (lane < s) { lb_m = 0.0f; rb_m = 0.0f; d1_m = 0.0f; }
        float la_p = __shfl_down(la, s, 64);
        float ra_p = __shfl_down(ra, s, 64);
        float d0_p = __shfl_down(d0, s, 64);
        if (lane + s > 63) { la_p = 0.0f; ra_p = 0.0f; d0_p = 0.0f; }

        float m00 = 1.0f - la * rb_m;
        float m01 = -ra * la_p;
        float m10 = -lb * rb_m;
        float m11 = 1.0f - rb * la_p;
        float idet = frcp(m00 * m11 - m01 * m10);

        float Lr0 = -la * lb_m, Lr1 = -lb * lb_m;
        float Rr0 = -ra * ra_p, Rr1 = -rb * ra_p;
        float e0 = d0 - la * d1_m - ra * d0_p;
        float e1 = d1 - lb * d1_m - rb * d0_p;

        la = idet * (m11 * Lr0 - m01 * Lr1);
        lb = idet * (m00 * Lr1 - m10 * Lr0);
        ra = idet * (m11 * Rr0 - m01 * Rr1);
        rb = idet * (m00 * Rr1 - m10 * Rr0);
        d0 = idet * (m11 * e0 - m01 * e1);
        d1 = idet * (m00 * e1 - m10 * e0);
    }
    float zl = __shfl_up(d1, 1, 64);
    if (lane == 0) zl = 0.0f;
    float yr = __shfl_down(d0, 1, 64);
    if (lane == 63) yr = 0.0f;

    #pragma unroll
    for (int r = 0; r < 16; ++r) Dv[r] = Dv[r] - Av[r] * zl - Cv[r] * yr;
    #pragma unroll
    for (int q = 0; q < 4; ++q) {
        float4 o;
        o.x = Dv[4 * q + 0];
        o.y = Dv[4 * q + 1];
        o.z = Dv[4 * q + 2];
        o.w = Dv[4 * q + 3];
        *(float4*)(orow + j0 + 4 * q) = o;
    }
}

extern "C" void kernel_launch(void* const* d_in, const int* in_sizes, int n_in,
                              void* d_out, int out_size, void* d_ws, size_t ws_size,
                              hipStream_t stream) {
    const float* fe = (const float*)d_in[0];
    const float* fi = (const float*)d_in[1];
    float* out = (float*)d_out;
    const size_t P = (size_t)NX * NV;

    float* fe1 = (float*)d_ws;
    float* fi1 = fe1 + P;
    float* se  = fi1 + P;
    float* si  = se + NX;
    float* se1 = si + NX;
    float* si1 = se1 + NX;

    dim3 rgrid(2048, 2);
    dim3 qgrid(512, 2);

    moments_kernel<<<512, 256, 0, stream>>>(fe, fi, se, si);
    stage1_kernel<<<rgrid, 256, 0, stream>>>(fe, fi, se, si, fe1, fi1, se1, si1);
    stage2_rhs_kernel<<<rgrid, 256, 0, stream>>>(fe, fi, fe1, fi1, se1, si1, out);
    collide_kernel<<<qgrid, 256, 0, stream>>>(out);
}